// Round 1
// baseline (1645.178 us; speedup 1.0000x reference)
//
#include <hip/hip_runtime.h>
#include <hip/hip_bf16.h>
#include <math.h>

#define SQ 2048
#define HDIM 1024
#define NHEAD 16
#define NKVH 4
#define HDSZ 64
#define NEXP 32
#define TOPK 4
#define ISZ 1024
#define MAXP (SQ*TOPK)            /* 8192 pairs */
#define MAXTILES (MAXP/64 + NEXP) /* 160 */

// ---------------- YaRN cos/sin table ----------------
__global__ void k_rope_table(const int* __restrict__ pos, float* __restrict__ cosb,
                             float* __restrict__ sinb) {
  int t = blockIdx.x, i = threadIdx.x;  // 32 threads
  float p = (float)pos[t];
  float lnT = logf(150000.0f);
  float freq = expf(lnT * (2.0f * i) / 64.0f);
  const float twopi = 6.28318530717958647692f;
  float low  = 32.0f * logf(4096.0f / (32.0f * twopi)) / lnT;
  float high = 32.0f * logf(4096.0f / (1.0f * twopi)) / lnT;
  float ramp = ((float)i - low) / (high - low);
  float mask = 1.0f - fminf(fmaxf(ramp, 0.0f), 1.0f);
  float inv_freq = (1.0f / (32.0f * freq)) * (1.0f - mask) + (1.0f / freq) * mask;
  float conc = 0.1f * logf(32.0f) + 1.0f;
  float f = p * inv_freq;
  cosb[t * 32 + i] = cosf(f) * conc;
  sinb[t * 32 + i] = sinf(f) * conc;
}

// ---------------- RMSNorm (one block per token, 256 thr) ----------------
__global__ __launch_bounds__(256) void k_rmsnorm(const float* __restrict__ in,
                                                 const float* __restrict__ w,
                                                 float* __restrict__ out) {
  int t = blockIdx.x, tid = threadIdx.x;
  float4 v = ((const float4*)(in + (size_t)t * HDIM))[tid];
  float ss = v.x * v.x + v.y * v.y + v.z * v.z + v.w * v.w;
  for (int off = 32; off >= 1; off >>= 1) ss += __shfl_xor(ss, off);
  __shared__ float red[4];
  if ((tid & 63) == 0) red[tid >> 6] = ss;
  __syncthreads();
  float tot = red[0] + red[1] + red[2] + red[3];
  float r = rsqrtf(tot * (1.0f / 1024.0f) + 1e-5f);
  float4 wv = ((const float4*)w)[tid];
  float4 o;
  o.x = v.x * r * wv.x; o.y = v.y * r * wv.y; o.z = v.z * r * wv.z; o.w = v.w * r * wv.w;
  ((float4*)(out + (size_t)t * HDIM))[tid] = o;
}

// ---------------- generic f32 GEMM: C[M,N] = A[M,1024] @ B[1024,N] (+resid) ----------------
__global__ __launch_bounds__(256) void k_gemm(const float* __restrict__ A,
                                              const float* __restrict__ B,
                                              const float* __restrict__ resid,
                                              float* __restrict__ C, int N) {
  int row0 = blockIdx.y * 64, col0 = blockIdx.x * 64;
  __shared__ float As[64][17];
  __shared__ float Bs[16][68];
  int tid = threadIdx.x, ty = tid >> 4, tx = tid & 15;
  float acc[4][4] = {};
  for (int k0 = 0; k0 < 1024; k0 += 16) {
    {
      int m = tid >> 2, kq = (tid & 3) * 4;
      float4 v = *(const float4*)(A + (size_t)(row0 + m) * 1024 + k0 + kq);
      As[m][kq] = v.x; As[m][kq + 1] = v.y; As[m][kq + 2] = v.z; As[m][kq + 3] = v.w;
    }
    {
      int k = tid >> 4, nq = (tid & 15) * 4;
      float4 v = *(const float4*)(B + (size_t)(k0 + k) * N + col0 + nq);
      Bs[k][nq] = v.x; Bs[k][nq + 1] = v.y; Bs[k][nq + 2] = v.z; Bs[k][nq + 3] = v.w;
    }
    __syncthreads();
#pragma unroll
    for (int kk = 0; kk < 16; kk++) {
      float a[4], b[4];
#pragma unroll
      for (int i = 0; i < 4; i++) a[i] = As[ty * 4 + i][kk];
#pragma unroll
      for (int j = 0; j < 4; j++) b[j] = Bs[kk][tx * 4 + j];
#pragma unroll
      for (int i = 0; i < 4; i++)
#pragma unroll
        for (int j = 0; j < 4; j++) acc[i][j] += a[i] * b[j];
    }
    __syncthreads();
  }
#pragma unroll
  for (int i = 0; i < 4; i++) {
    int r = row0 + ty * 4 + i;
#pragma unroll
    for (int j = 0; j < 4; j++) {
      int c = col0 + tx * 4 + j;
      float v = acc[i][j];
      if (resid) v += resid[(size_t)r * N + c];
      C[(size_t)r * N + c] = v;
    }
  }
}

// ---------------- RoPE apply (in-place on q and k) ----------------
__global__ __launch_bounds__(256) void k_rope_apply(float* __restrict__ qb, float* __restrict__ kb,
                                                    const float* __restrict__ cosb,
                                                    const float* __restrict__ sinb) {
  int t = blockIdx.x;
  const float* cs = cosb + t * 32;
  const float* sn = sinb + t * 32;
  for (int p = threadIdx.x; p < (NHEAD + NKVH) * 32; p += blockDim.x) {
    int head = p >> 5, i = p & 31;
    float c = cs[i], s = sn[i];
    float* base = (head < NHEAD) ? (qb + (size_t)t * 1024 + head * 64)
                                 : (kb + (size_t)t * 256 + (head - NHEAD) * 64);
    float lo = base[i], hi = base[i + 32];
    base[i] = lo * c - hi * s;
    base[i + 32] = hi * c + lo * s;
  }
}

// ---------------- sliding-window attention with sink (1 wave = 1 (head,query)) ----------------
__global__ __launch_bounds__(256) void k_attn(const float* __restrict__ qb,
                                              const float* __restrict__ kb,
                                              const float* __restrict__ vb,
                                              const float* __restrict__ sinks,
                                              float* __restrict__ attnb) {
  int wid = threadIdx.x >> 6, lane = threadIdx.x & 63;
  int t = blockIdx.x * 4 + wid;
  int h = blockIdx.y;
  int kvh = h >> 2;
  __shared__ float qs[4][64];
  __shared__ float ps[4][128];
  qs[wid][lane] = qb[(size_t)t * 1024 + h * 64 + lane];
  __syncthreads();
  int start = t - 127; if (start < 0) start = 0;
  int n = t - start + 1;
  float sc[2];
#pragma unroll
  for (int r = 0; r < 2; r++) {
    int j = lane + r * 64;
    float d = -1e30f;
    if (j < n) {
      const float* kp = kb + (size_t)(start + j) * 256 + kvh * 64;
      float acc = 0.0f;
#pragma unroll
      for (int ii = 0; ii < 64; ii += 4) {
        float4 kv = *(const float4*)(kp + ii);
        acc += qs[wid][ii] * kv.x + qs[wid][ii + 1] * kv.y + qs[wid][ii + 2] * kv.z +
               qs[wid][ii + 3] * kv.w;
      }
      d = acc * 0.125f;
    }
    sc[r] = d;
  }
  float m = fmaxf(sc[0], sc[1]);
  for (int off = 32; off >= 1; off >>= 1) m = fmaxf(m, __shfl_xor(m, off));
  float snk = sinks[h];
  m = fmaxf(m, snk);
  float p0 = (sc[0] > -1e29f) ? expf(sc[0] - m) : 0.0f;
  float p1 = (sc[1] > -1e29f) ? expf(sc[1] - m) : 0.0f;
  float dsum = p0 + p1;
  for (int off = 32; off >= 1; off >>= 1) dsum += __shfl_xor(dsum, off);
  dsum += expf(snk - m);
  ps[wid][lane] = p0;
  ps[wid][lane + 64] = p1;
  __syncthreads();
  float inv = 1.0f / dsum;
  float acc = 0.0f;
  for (int j = 0; j < n; j++)
    acc += ps[wid][j] * vb[(size_t)(start + j) * 256 + kvh * 64 + lane];
  attnb[(size_t)t * 1024 + h * 64 + lane] = acc * inv;
}

// ---------------- router: logits -> top4 -> softmax weights (1 wave per token) ----------------
__global__ __launch_bounds__(64) void k_router(const float* __restrict__ x2,
                                               const float* __restrict__ rw,
                                               const float* __restrict__ rb,
                                               int* __restrict__ top4i, float* __restrict__ top4w,
                                               int* __restrict__ counts) {
  int t = blockIdx.x, lane = threadIdx.x;
  int e = lane & 31, half = lane >> 5;
  const float* x = x2 + (size_t)t * 1024 + half * 512;
  const float* w = rw + (size_t)half * 512 * 32 + e;
  float acc = 0.0f;
  for (int j = 0; j < 512; j++) acc += x[j] * w[(size_t)j * 32];
  acc += __shfl_xor(acc, 32);
  __shared__ float lg[32];
  if (lane < 32) lg[e] = acc + rb[e];
  __syncthreads();
  if (lane == 0) {
    float v[32];
    for (int i = 0; i < 32; i++) v[i] = lg[i];
    int bi[4]; float bv[4];
    for (int kk = 0; kk < 4; kk++) {
      int best = 0; float bvv = -1e30f;
      for (int i = 0; i < 32; i++)
        if (v[i] > bvv) { bvv = v[i]; best = i; }
      bi[kk] = best; bv[kk] = bvv; v[best] = -1e30f;
    }
    float mx = bv[0], ssum = 0.0f, ex[4];
    for (int kk = 0; kk < 4; kk++) { ex[kk] = expf(bv[kk] - mx); ssum += ex[kk]; }
    for (int kk = 0; kk < 4; kk++) {
      top4i[t * 4 + kk] = bi[kk];
      top4w[t * 4 + kk] = ex[kk] / ssum;
      atomicAdd(&counts[bi[kk]], 1);
    }
  }
}

// ---------------- expert offsets + tile descriptors (single thread; E=32) ----------------
__global__ void k_offsets(const int* __restrict__ counts, int* __restrict__ offs,
                          int* __restrict__ ntiles, int* __restrict__ tile_e,
                          int* __restrict__ tile_row, int* __restrict__ tile_end) {
  if (threadIdx.x == 0 && blockIdx.x == 0) {
    int acc = 0, nt = 0;
    for (int e = 0; e < NEXP; e++) {
      offs[e] = acc;
      int end = acc + counts[e];
      for (int r = acc; r < end; r += 64) { tile_e[nt] = e; tile_row[nt] = r; tile_end[nt] = end; nt++; }
      acc = end;
    }
    offs[NEXP] = acc;
    *ntiles = nt;
  }
}

// ---------------- scatter tokens into per-expert buckets ----------------
__global__ void k_scatter(const int* __restrict__ top4i, const float* __restrict__ top4w,
                          const int* __restrict__ offs, int* __restrict__ cursor,
                          int* __restrict__ pair_token, float* __restrict__ pair_wt) {
  int t = blockIdx.x * blockDim.x + threadIdx.x;
  if (t >= SQ) return;
  for (int kk = 0; kk < 4; kk++) {
    int e = top4i[t * 4 + kk];
    int pos = atomicAdd(&cursor[e], 1);
    int p = offs[e] + pos;
    pair_token[p] = t;
    pair_wt[p] = top4w[t * 4 + kk];
  }
}

// ---------------- MoE gate+up GEMM with fused activation -> hmid ----------------
__global__ __launch_bounds__(256) void k_moe_gate_up(
    const float* __restrict__ x2, const float* __restrict__ wg, const float* __restrict__ bg,
    const float* __restrict__ wu, const float* __restrict__ bu,
    const int* __restrict__ pair_token, const int* __restrict__ tile_e,
    const int* __restrict__ tile_row, const int* __restrict__ tile_end,
    const int* __restrict__ ntiles, float* __restrict__ hmid) {
  int tile = blockIdx.y;
  if (tile >= *ntiles) return;
  int e = tile_e[tile], row0 = tile_row[tile], rend = tile_end[tile];
  int col0 = blockIdx.x * 64;
  __shared__ float As[64][17];
  __shared__ float Bg[16][68];
  __shared__ float Bu[16][68];
  __shared__ int tk[64];
  int tid = threadIdx.x, ty = tid >> 4, tx = tid & 15;
  if (tid < 64) { int p = row0 + tid; tk[tid] = (p < rend) ? pair_token[p] : -1; }
  __syncthreads();
  const float* wge = wg + (size_t)e * 1024 * 1024;
  const float* wue = wu + (size_t)e * 1024 * 1024;
  float accg[4][4] = {}, accu[4][4] = {};
  for (int k0 = 0; k0 < 1024; k0 += 16) {
    {
      int m = tid >> 2, kq = (tid & 3) * 4;
      int tok = tk[m];
      float4 v = make_float4(0.f, 0.f, 0.f, 0.f);
      if (tok >= 0) v = *(const float4*)(x2 + (size_t)tok * 1024 + k0 + kq);
      As[m][kq] = v.x; As[m][kq + 1] = v.y; As[m][kq + 2] = v.z; As[m][kq + 3] = v.w;
    }
    {
      int k = tid >> 4, nq = (tid & 15) * 4;
      float4 vg = *(const float4*)(wge + (size_t)(k0 + k) * 1024 + col0 + nq);
      float4 vu = *(const float4*)(wue + (size_t)(k0 + k) * 1024 + col0 + nq);
      Bg[k][nq] = vg.x; Bg[k][nq + 1] = vg.y; Bg[k][nq + 2] = vg.z; Bg[k][nq + 3] = vg.w;
      Bu[k][nq] = vu.x; Bu[k][nq + 1] = vu.y; Bu[k][nq + 2] = vu.z; Bu[k][nq + 3] = vu.w;
    }
    __syncthreads();
#pragma unroll
    for (int kk = 0; kk < 16; kk++) {
      float a[4], g[4], u[4];
#pragma unroll
      for (int i = 0; i < 4; i++) a[i] = As[ty * 4 + i][kk];
#pragma unroll
      for (int j = 0; j < 4; j++) { g[j] = Bg[kk][tx * 4 + j]; u[j] = Bu[kk][tx * 4 + j]; }
#pragma unroll
      for (int i = 0; i < 4; i++)
#pragma unroll
        for (int j = 0; j < 4; j++) { accg[i][j] += a[i] * g[j]; accu[i][j] += a[i] * u[j]; }
    }
    __syncthreads();
  }
#pragma unroll
  for (int i = 0; i < 4; i++) {
    int p = row0 + ty * 4 + i;
    if (p >= rend) continue;
#pragma unroll
    for (int j = 0; j < 4; j++) {
      int ic = col0 + tx * 4 + j;
      float g = accg[i][j] + bg[e * 1024 + ic];
      g = fminf(g, 7.0f);
      float u = accu[i][j] + bu[e * 1024 + ic];
      u = fminf(fmaxf(u, -7.0f), 7.0f);
      float sg = 1.0f / (1.0f + expf(-1.702f * g));
      hmid[(size_t)p * 1024 + ic] = (u + 1.0f) * (g * sg);
    }
  }
}

// ---------------- MoE down GEMM, weighted atomic scatter into residual out ----------------
__global__ __launch_bounds__(256) void k_moe_down(
    const float* __restrict__ hmid, const float* __restrict__ wd, const float* __restrict__ bd,
    const int* __restrict__ pair_token, const float* __restrict__ pair_wt,
    const int* __restrict__ tile_e, const int* __restrict__ tile_row,
    const int* __restrict__ tile_end, const int* __restrict__ ntiles, float* __restrict__ out) {
  int tile = blockIdx.y;
  if (tile >= *ntiles) return;
  int e = tile_e[tile], row0 = tile_row[tile], rend = tile_end[tile];
  int col0 = blockIdx.x * 64;
  __shared__ float As[64][17];
  __shared__ float Bs[16][68];
  int tid = threadIdx.x, ty = tid >> 4, tx = tid & 15;
  const float* wde = wd + (size_t)e * 1024 * 1024;
  float acc[4][4] = {};
  for (int k0 = 0; k0 < 1024; k0 += 16) {
    {
      int m = tid >> 2, kq = (tid & 3) * 4;
      int p = row0 + m;
      float4 v = make_float4(0.f, 0.f, 0.f, 0.f);
      if (p < rend) v = *(const float4*)(hmid + (size_t)p * 1024 + k0 + kq);
      As[m][kq] = v.x; As[m][kq + 1] = v.y; As[m][kq + 2] = v.z; As[m][kq + 3] = v.w;
    }
    {
      int k = tid >> 4, nq = (tid & 15) * 4;
      float4 v = *(const float4*)(wde + (size_t)(k0 + k) * 1024 + col0 + nq);
      Bs[k][nq] = v.x; Bs[k][nq + 1] = v.y; Bs[k][nq + 2] = v.z; Bs[k][nq + 3] = v.w;
    }
    __syncthreads();
#pragma unroll
    for (int kk = 0; kk < 16; kk++) {
      float a[4], b[4];
#pragma unroll
      for (int i = 0; i < 4; i++) a[i] = As[ty * 4 + i][kk];
#pragma unroll
      for (int j = 0; j < 4; j++) b[j] = Bs[kk][tx * 4 + j];
#pragma unroll
      for (int i = 0; i < 4; i++)
#pragma unroll
        for (int j = 0; j < 4; j++) acc[i][j] += a[i] * b[j];
    }
    __syncthreads();
  }
#pragma unroll
  for (int i = 0; i < 4; i++) {
    int p = row0 + ty * 4 + i;
    if (p >= rend) continue;
    int t = pair_token[p];
    float wtp = pair_wt[p];
#pragma unroll
    for (int j = 0; j < 4; j++) {
      int c = col0 + tx * 4 + j;
      float val = (acc[i][j] + bd[e * 1024 + c]) * wtp;
      atomicAdd(&out[(size_t)t * 1024 + c], val);
    }
  }
}

extern "C" void kernel_launch(void* const* d_in, const int* in_sizes, int n_in, void* d_out,
                              int out_size, void* d_ws, size_t ws_size, hipStream_t stream) {
  const float* hs   = (const float*)d_in[0];
  const int*   pos  = (const int*)d_in[1];
  const float* ln1  = (const float*)d_in[2];
  const float* ln2  = (const float*)d_in[3];
  const float* wq   = (const float*)d_in[4];
  const float* wk   = (const float*)d_in[5];
  const float* wv   = (const float*)d_in[6];
  const float* wo   = (const float*)d_in[7];
  const float* sinks = (const float*)d_in[8];
  const float* rw   = (const float*)d_in[9];
  const float* rb   = (const float*)d_in[10];
  const float* wg   = (const float*)d_in[11];
  const float* bg   = (const float*)d_in[12];
  const float* wu   = (const float*)d_in[13];
  const float* bu   = (const float*)d_in[14];
  const float* wd   = (const float*)d_in[15];
  const float* bd   = (const float*)d_in[16];
  float* out = (float*)d_out;

  float* ws = (float*)d_ws;
  size_t o = 0;
  float* cosb  = ws + o; o += SQ * 32;
  float* sinb  = ws + o; o += SQ * 32;
  float* x1    = ws + o; o += (size_t)SQ * 1024;
  float* qb    = ws + o; o += (size_t)SQ * 1024;
  float* kbuf  = ws + o; o += (size_t)SQ * 256;
  float* vbuf  = ws + o; o += (size_t)SQ * 256;
  float* attnb = ws + o; o += (size_t)SQ * 1024;
  float* x2    = ws + o; o += (size_t)SQ * 1024;
  float* hmid  = ws + o; o += (size_t)MAXP * 1024;
  float* pair_wt = ws + o; o += MAXP;
  float* top4w = ws + o; o += SQ * 4;
  int* ib = (int*)(ws + o);
  int* pair_token = ib; ib += MAXP;
  int* top4i  = ib; ib += SQ * 4;
  int* counts = ib; ib += 32;   // counts+cursor contiguous: one memset
  int* cursor = ib; ib += 32;
  int* offs   = ib; ib += 33;
  int* ntiles = ib; ib += 1;
  int* tile_e = ib; ib += MAXTILES;
  int* tile_row = ib; ib += MAXTILES;
  int* tile_end = ib; ib += MAXTILES;

  hipMemsetAsync(counts, 0, 64 * sizeof(int), stream);

  k_rope_table<<<SQ, 32, 0, stream>>>(pos, cosb, sinb);
  k_rmsnorm<<<SQ, 256, 0, stream>>>(hs, ln1, x1);
  k_gemm<<<dim3(16, 32), 256, 0, stream>>>(x1, wq, nullptr, qb, 1024);
  k_gemm<<<dim3(4, 32), 256, 0, stream>>>(x1, wk, nullptr, kbuf, 256);
  k_gemm<<<dim3(4, 32), 256, 0, stream>>>(x1, wv, nullptr, vbuf, 256);
  k_rope_apply<<<SQ, 256, 0, stream>>>(qb, kbuf, cosb, sinb);
  k_attn<<<dim3(SQ / 4, NHEAD), 256, 0, stream>>>(qb, kbuf, vbuf, sinks, attnb);
  k_gemm<<<dim3(16, 32), 256, 0, stream>>>(attnb, wo, hs, out, 1024);  // out = hs + attn@wo
  k_rmsnorm<<<SQ, 256, 0, stream>>>(out, ln2, x2);
  k_router<<<SQ, 64, 0, stream>>>(x2, rw, rb, top4i, top4w, counts);
  k_offsets<<<1, 1, 0, stream>>>(counts, offs, ntiles, tile_e, tile_row, tile_end);
  k_scatter<<<(SQ + 255) / 256, 256, 0, stream>>>(top4i, top4w, offs, cursor, pair_token, pair_wt);
  k_moe_gate_up<<<dim3(16, MAXTILES), 256, 0, stream>>>(x2, wg, bg, wu, bu, pair_token, tile_e,
                                                        tile_row, tile_end, ntiles, hmid);
  k_moe_down<<<dim3(16, MAXTILES), 256, 0, stream>>>(hmid, wd, bd, pair_token, pair_wt, tile_e,
                                                     tile_row, tile_end, ntiles, out);
}

// Round 2
// 1080.166 us; speedup vs baseline: 1.5231x; 1.5231x over previous
//
#include <hip/hip_runtime.h>
#include <hip/hip_bf16.h>
#include <math.h>

#define SQ 2048
#define HDIM 1024
#define NHEAD 16
#define NKVH 4
#define NEXP 32
#define MAXP (SQ*4)               /* 8192 pairs */
#define MTS 128                   /* MoE row-tile size */
#define MAXTILES (MAXP/MTS + NEXP) /* 96 */

typedef __attribute__((ext_vector_type(8))) short short8v;
typedef __attribute__((ext_vector_type(4))) float floatx4;

__device__ __forceinline__ unsigned short bf16b(float f) {
  __hip_bfloat16 h = __float2bfloat16(f);
  return *reinterpret_cast<unsigned short*>(&h);
}
__device__ __forceinline__ unsigned int packbf(float a, float b) {
  return (unsigned int)bf16b(a) | ((unsigned int)bf16b(b) << 16);
}

// ---------------- YaRN cos/sin table ----------------
__global__ void k_rope_table(const int* __restrict__ pos, float* __restrict__ cosb,
                             float* __restrict__ sinb) {
  int t = blockIdx.x, i = threadIdx.x;  // 32 threads
  float p = (float)pos[t];
  float lnT = logf(150000.0f);
  float freq = expf(lnT * (2.0f * i) / 64.0f);
  const float twopi = 6.28318530717958647692f;
  float low  = 32.0f * logf(4096.0f / (32.0f * twopi)) / lnT;
  float high = 32.0f * logf(4096.0f / (1.0f * twopi)) / lnT;
  float ramp = ((float)i - low) / (high - low);
  float mask = 1.0f - fminf(fmaxf(ramp, 0.0f), 1.0f);
  float inv_freq = (1.0f / (32.0f * freq)) * (1.0f - mask) + (1.0f / freq) * mask;
  float conc = 0.1f * logf(32.0f) + 1.0f;
  float f = p * inv_freq;
  cosb[t * 32 + i] = cosf(f) * conc;
  sinb[t * 32 + i] = sinf(f) * conc;
}

// ---------------- RMSNorm ----------------
__global__ __launch_bounds__(256) void k_rmsnorm(const float* __restrict__ in,
                                                 const float* __restrict__ w,
                                                 float* __restrict__ out) {
  int t = blockIdx.x, tid = threadIdx.x;
  float4 v = ((const float4*)(in + (size_t)t * HDIM))[tid];
  float ss = v.x * v.x + v.y * v.y + v.z * v.z + v.w * v.w;
  for (int off = 32; off >= 1; off >>= 1) ss += __shfl_xor(ss, off);
  __shared__ float red[4];
  if ((tid & 63) == 0) red[tid >> 6] = ss;
  __syncthreads();
  float tot = red[0] + red[1] + red[2] + red[3];
  float r = rsqrtf(tot * (1.0f / 1024.0f) + 1e-5f);
  float4 wv = ((const float4*)w)[tid];
  float4 o;
  o.x = v.x * r * wv.x; o.y = v.y * r * wv.y; o.z = v.z * r * wv.z; o.w = v.w * r * wv.w;
  ((float4*)(out + (size_t)t * HDIM))[tid] = o;
}

// ---------------- f32 → bf16 bulk convert ----------------
__global__ __launch_bounds__(256) void k_cvt_bf16(const float* __restrict__ in,
                                                  unsigned short* __restrict__ out) {
  int i = (blockIdx.x * 256 + threadIdx.x) * 4;
  float4 v = *(const float4*)(in + i);
  ushort4 o;
  o.x = bf16b(v.x); o.y = bf16b(v.y); o.z = bf16b(v.z); o.w = bf16b(v.w);
  *(ushort4*)(out + i) = o;
}

// ---------------- generic f32 GEMM (dense projections) ----------------
__global__ __launch_bounds__(256) void k_gemm(const float* __restrict__ A,
                                              const float* __restrict__ B,
                                              const float* __restrict__ resid,
                                              float* __restrict__ C, int N) {
  int row0 = blockIdx.y * 64, col0 = blockIdx.x * 64;
  __shared__ float As[64][17];
  __shared__ float Bs[16][68];
  int tid = threadIdx.x, ty = tid >> 4, tx = tid & 15;
  float acc[4][4] = {};
  for (int k0 = 0; k0 < 1024; k0 += 16) {
    {
      int m = tid >> 2, kq = (tid & 3) * 4;
      float4 v = *(const float4*)(A + (size_t)(row0 + m) * 1024 + k0 + kq);
      As[m][kq] = v.x; As[m][kq + 1] = v.y; As[m][kq + 2] = v.z; As[m][kq + 3] = v.w;
    }
    {
      int k = tid >> 4, nq = (tid & 15) * 4;
      float4 v = *(const float4*)(B + (size_t)(k0 + k) * N + col0 + nq);
      Bs[k][nq] = v.x; Bs[k][nq + 1] = v.y; Bs[k][nq + 2] = v.z; Bs[k][nq + 3] = v.w;
    }
    __syncthreads();
#pragma unroll
    for (int kk = 0; kk < 16; kk++) {
      float a[4], b[4];
#pragma unroll
      for (int i = 0; i < 4; i++) a[i] = As[ty * 4 + i][kk];
#pragma unroll
      for (int j = 0; j < 4; j++) b[j] = Bs[kk][tx * 4 + j];
#pragma unroll
      for (int i = 0; i < 4; i++)
#pragma unroll
        for (int j = 0; j < 4; j++) acc[i][j] += a[i] * b[j];
    }
    __syncthreads();
  }
#pragma unroll
  for (int i = 0; i < 4; i++) {
    int r = row0 + ty * 4 + i;
#pragma unroll
    for (int j = 0; j < 4; j++) {
      int c = col0 + tx * 4 + j;
      float v = acc[i][j];
      if (resid) v += resid[(size_t)r * N + c];
      C[(size_t)r * N + c] = v;
    }
  }
}

// ---------------- RoPE apply ----------------
__global__ __launch_bounds__(256) void k_rope_apply(float* __restrict__ qb, float* __restrict__ kb,
                                                    const float* __restrict__ cosb,
                                                    const float* __restrict__ sinb) {
  int t = blockIdx.x;
  const float* cs = cosb + t * 32;
  const float* sn = sinb + t * 32;
  for (int p = threadIdx.x; p < (NHEAD + NKVH) * 32; p += blockDim.x) {
    int head = p >> 5, i = p & 31;
    float c = cs[i], s = sn[i];
    float* base = (head < NHEAD) ? (qb + (size_t)t * 1024 + head * 64)
                                 : (kb + (size_t)t * 256 + (head - NHEAD) * 64);
    float lo = base[i], hi = base[i + 32];
    base[i] = lo * c - hi * s;
    base[i + 32] = hi * c + lo * s;
  }
}

// ---------------- sliding-window attention with sink ----------------
__global__ __launch_bounds__(256) void k_attn(const float* __restrict__ qb,
                                              const float* __restrict__ kb,
                                              const float* __restrict__ vb,
                                              const float* __restrict__ sinks,
                                              float* __restrict__ attnb) {
  int wid = threadIdx.x >> 6, lane = threadIdx.x & 63;
  int t = blockIdx.x * 4 + wid;
  int h = blockIdx.y;
  int kvh = h >> 2;
  __shared__ float qs[4][64];
  __shared__ float ps[4][128];
  qs[wid][lane] = qb[(size_t)t * 1024 + h * 64 + lane];
  __syncthreads();
  int start = t - 127; if (start < 0) start = 0;
  int n = t - start + 1;
  float sc[2];
#pragma unroll
  for (int r = 0; r < 2; r++) {
    int j = lane + r * 64;
    float d = -1e30f;
    if (j < n) {
      const float* kp = kb + (size_t)(start + j) * 256 + kvh * 64;
      float acc = 0.0f;
#pragma unroll
      for (int ii = 0; ii < 64; ii += 4) {
        float4 kv = *(const float4*)(kp + ii);
        acc += qs[wid][ii] * kv.x + qs[wid][ii + 1] * kv.y + qs[wid][ii + 2] * kv.z +
               qs[wid][ii + 3] * kv.w;
      }
      d = acc * 0.125f;
    }
    sc[r] = d;
  }
  float m = fmaxf(sc[0], sc[1]);
  for (int off = 32; off >= 1; off >>= 1) m = fmaxf(m, __shfl_xor(m, off));
  float snk = sinks[h];
  m = fmaxf(m, snk);
  float p0 = (sc[0] > -1e29f) ? expf(sc[0] - m) : 0.0f;
  float p1 = (sc[1] > -1e29f) ? expf(sc[1] - m) : 0.0f;
  float dsum = p0 + p1;
  for (int off = 32; off >= 1; off >>= 1) dsum += __shfl_xor(dsum, off);
  dsum += expf(snk - m);
  ps[wid][lane] = p0;
  ps[wid][lane + 64] = p1;
  __syncthreads();
  float inv = 1.0f / dsum;
  float acc = 0.0f;
  for (int j = 0; j < n; j++)
    acc += ps[wid][j] * vb[(size_t)(start + j) * 256 + kvh * 64 + lane];
  attnb[(size_t)t * 1024 + h * 64 + lane] = acc * inv;
}

// ---------------- router (f32, exact) ----------------
__global__ __launch_bounds__(64) void k_router(const float* __restrict__ x2,
                                               const float* __restrict__ rw,
                                               const float* __restrict__ rb,
                                               int* __restrict__ top4i, float* __restrict__ top4w,
                                               int* __restrict__ counts) {
  int t = blockIdx.x, lane = threadIdx.x;
  int e = lane & 31, half = lane >> 5;
  const float* x = x2 + (size_t)t * 1024 + half * 512;
  const float* w = rw + (size_t)half * 512 * 32 + e;
  float acc = 0.0f;
  for (int j = 0; j < 512; j++) acc += x[j] * w[(size_t)j * 32];
  acc += __shfl_xor(acc, 32);
  __shared__ float lg[32];
  if (lane < 32) lg[e] = acc + rb[e];
  __syncthreads();
  if (lane == 0) {
    float v[32];
    for (int i = 0; i < 32; i++) v[i] = lg[i];
    int bi[4]; float bv[4];
    for (int kk = 0; kk < 4; kk++) {
      int best = 0; float bvv = -1e30f;
      for (int i = 0; i < 32; i++)
        if (v[i] > bvv) { bvv = v[i]; best = i; }
      bi[kk] = best; bv[kk] = bvv; v[best] = -1e30f;
    }
    float mx = bv[0], ssum = 0.0f, ex[4];
    for (int kk = 0; kk < 4; kk++) { ex[kk] = expf(bv[kk] - mx); ssum += ex[kk]; }
    for (int kk = 0; kk < 4; kk++) {
      top4i[t * 4 + kk] = bi[kk];
      top4w[t * 4 + kk] = ex[kk] / ssum;
      atomicAdd(&counts[bi[kk]], 1);
    }
  }
}

// ---------------- expert offsets + tile descriptors (MTS=128) ----------------
__global__ void k_offsets(const int* __restrict__ counts, int* __restrict__ offs,
                          int* __restrict__ ntiles, int* __restrict__ tile_e,
                          int* __restrict__ tile_row, int* __restrict__ tile_end) {
  if (threadIdx.x == 0 && blockIdx.x == 0) {
    int acc = 0, nt = 0;
    for (int e = 0; e < NEXP; e++) {
      offs[e] = acc;
      int end = acc + counts[e];
      for (int r = acc; r < end; r += MTS) { tile_e[nt] = e; tile_row[nt] = r; tile_end[nt] = end; nt++; }
      acc = end;
    }
    offs[NEXP] = acc;
    *ntiles = nt;
  }
}

// ---------------- scatter tokens into per-expert buckets ----------------
__global__ void k_scatter(const int* __restrict__ top4i, const float* __restrict__ top4w,
                          const int* __restrict__ offs, int* __restrict__ cursor,
                          int* __restrict__ pair_token, float* __restrict__ pair_wt) {
  int t = blockIdx.x * blockDim.x + threadIdx.x;
  if (t >= SQ) return;
  for (int kk = 0; kk < 4; kk++) {
    int e = top4i[t * 4 + kk];
    int pos = atomicAdd(&cursor[e], 1);
    int p = offs[e] + pos;
    pair_token[p] = t;
    pair_wt[p] = top4w[t * 4 + kk];
  }
}

// ---------------- MoE gate+up: bf16 MFMA, f32 weights converted in staging ----------------
// tile: 128 pairs x 64 cols, 4 waves (2x2), wave = 64x32, frag 16x16x32
__global__ __launch_bounds__(256) void k_moe_gate_up_mfma(
    const unsigned short* __restrict__ x2bf, const float* __restrict__ wg,
    const float* __restrict__ bg, const float* __restrict__ wu, const float* __restrict__ bu,
    const int* __restrict__ pair_token, const int* __restrict__ tile_e,
    const int* __restrict__ tile_row, const int* __restrict__ tile_end,
    const int* __restrict__ ntiles, unsigned short* __restrict__ hmidbf) {
  int tile = blockIdx.y;
  if (tile >= *ntiles) return;
  int e = tile_e[tile], row0 = tile_row[tile], rend = tile_end[tile];
  int col0 = blockIdx.x * 64;
  __shared__ unsigned short As[128][40];   // [row][k], +8 pad (stride 80B)
  __shared__ unsigned short Bg[64][40];    // [col][k]
  __shared__ unsigned short Bu[64][40];
  __shared__ int tk[128];
  int tid = threadIdx.x;
  if (tid < 128) { int p = row0 + tid; tk[tid] = (p < rend) ? pair_token[p] : -1; }
  int lane = tid & 63, wv = tid >> 6, wr = wv >> 1, wc = wv & 1;
  int fr = lane & 15, fks = (lane >> 4) * 8;
  const float* wge = wg + (size_t)e * (1024 * 1024);
  const float* wue = wu + (size_t)e * (1024 * 1024);
  int am = tid & 127, akh = tid >> 7;       // A staging: row, k-half(16)
  int bi = tid & 63, bks = (tid >> 6) * 8;  // B staging: col, k-seg(8)
  floatx4 accg[4][2] = {{{0.f,0.f,0.f,0.f}}};
  floatx4 accu[4][2] = {{{0.f,0.f,0.f,0.f}}};
  __syncthreads();
  for (int k0 = 0; k0 < 1024; k0 += 32) {
    {  // A: gathered bf16 rows, k-contiguous
      int tok = tk[am];
      uint4 v0 = make_uint4(0, 0, 0, 0), v1 = v0;
      if (tok >= 0) {
        const uint4* src = (const uint4*)(x2bf + (size_t)tok * 1024 + k0 + akh * 16);
        v0 = src[0]; v1 = src[1];
      }
      *(uint4*)&As[am][akh * 16] = v0;
      *(uint4*)&As[am][akh * 16 + 8] = v1;
    }
    {  // B: f32 global (coalesced per k-row), cvt->bf16, write [col][k]
      const float* pg = wge + (size_t)(k0 + bks) * 1024 + col0 + bi;
      const float* pu = wue + (size_t)(k0 + bks) * 1024 + col0 + bi;
      unsigned int g[4], u[4];
#pragma unroll
      for (int j = 0; j < 4; j++) {
        g[j] = packbf(pg[(size_t)(2 * j) * 1024], pg[(size_t)(2 * j + 1) * 1024]);
        u[j] = packbf(pu[(size_t)(2 * j) * 1024], pu[(size_t)(2 * j + 1) * 1024]);
      }
      *(uint4*)&Bg[bi][bks] = make_uint4(g[0], g[1], g[2], g[3]);
      *(uint4*)&Bu[bi][bks] = make_uint4(u[0], u[1], u[2], u[3]);
    }
    __syncthreads();
    short8v a[4], bgv[2], buv[2];
#pragma unroll
    for (int mi = 0; mi < 4; mi++) a[mi] = *(const short8v*)&As[wr * 64 + mi * 16 + fr][fks];
#pragma unroll
    for (int ni = 0; ni < 2; ni++) {
      bgv[ni] = *(const short8v*)&Bg[wc * 32 + ni * 16 + fr][fks];
      buv[ni] = *(const short8v*)&Bu[wc * 32 + ni * 16 + fr][fks];
    }
#pragma unroll
    for (int mi = 0; mi < 4; mi++)
#pragma unroll
      for (int ni = 0; ni < 2; ni++) {
        accg[mi][ni] = __builtin_amdgcn_mfma_f32_16x16x32_bf16(a[mi], bgv[ni], accg[mi][ni], 0, 0, 0);
        accu[mi][ni] = __builtin_amdgcn_mfma_f32_16x16x32_bf16(a[mi], buv[ni], accu[mi][ni], 0, 0, 0);
      }
    __syncthreads();
  }
  int fg = lane >> 4;
#pragma unroll
  for (int mi = 0; mi < 4; mi++)
#pragma unroll
    for (int r = 0; r < 4; r++) {
      int p = row0 + wr * 64 + mi * 16 + fg * 4 + r;
      if (p >= rend) continue;
#pragma unroll
      for (int ni = 0; ni < 2; ni++) {
        int ic = col0 + wc * 32 + ni * 16 + fr;
        float g = accg[mi][ni][r] + bg[e * 1024 + ic];
        g = fminf(g, 7.0f);
        float u = accu[mi][ni][r] + bu[e * 1024 + ic];
        u = fminf(fmaxf(u, -7.0f), 7.0f);
        float sg = 1.0f / (1.0f + expf(-1.702f * g));
        hmidbf[(size_t)p * 1024 + ic] = bf16b((u + 1.0f) * (g * sg));
      }
    }
}

// ---------------- MoE down: bf16 MFMA, weighted atomic scatter ----------------
__global__ __launch_bounds__(256) void k_moe_down_mfma(
    const unsigned short* __restrict__ hmidbf, const float* __restrict__ wd,
    const float* __restrict__ bd, const int* __restrict__ pair_token,
    const float* __restrict__ pair_wt, const int* __restrict__ tile_e,
    const int* __restrict__ tile_row, const int* __restrict__ tile_end,
    const int* __restrict__ ntiles, float* __restrict__ out) {
  int tile = blockIdx.y;
  if (tile >= *ntiles) return;
  int e = tile_e[tile], row0 = tile_row[tile], rend = tile_end[tile];
  int col0 = blockIdx.x * 64;
  __shared__ unsigned short As[128][40];
  __shared__ unsigned short Bs[64][40];
  int tid = threadIdx.x;
  int lane = tid & 63, wv = tid >> 6, wr = wv >> 1, wc = wv & 1;
  int fr = lane & 15, fks = (lane >> 4) * 8;
  const float* wde = wd + (size_t)e * (1024 * 1024);
  int am = tid & 127, akh = tid >> 7;
  int bi = tid & 63, bks = (tid >> 6) * 8;
  floatx4 acc[4][2] = {{{0.f,0.f,0.f,0.f}}};
  for (int k0 = 0; k0 < 1024; k0 += 32) {
    {
      int p = row0 + am;
      uint4 v0 = make_uint4(0, 0, 0, 0), v1 = v0;
      if (p < rend) {
        const uint4* src = (const uint4*)(hmidbf + (size_t)p * 1024 + k0 + akh * 16);
        v0 = src[0]; v1 = src[1];
      }
      *(uint4*)&As[am][akh * 16] = v0;
      *(uint4*)&As[am][akh * 16 + 8] = v1;
    }
    {
      const float* pd = wde + (size_t)(k0 + bks) * 1024 + col0 + bi;
      unsigned int d[4];
#pragma unroll
      for (int j = 0; j < 4; j++)
        d[j] = packbf(pd[(size_t)(2 * j) * 1024], pd[(size_t)(2 * j + 1) * 1024]);
      *(uint4*)&Bs[bi][bks] = make_uint4(d[0], d[1], d[2], d[3]);
    }
    __syncthreads();
    short8v a[4], b[2];
#pragma unroll
    for (int mi = 0; mi < 4; mi++) a[mi] = *(const short8v*)&As[wr * 64 + mi * 16 + fr][fks];
#pragma unroll
    for (int ni = 0; ni < 2; ni++) b[ni] = *(const short8v*)&Bs[wc * 32 + ni * 16 + fr][fks];
#pragma unroll
    for (int mi = 0; mi < 4; mi++)
#pragma unroll
      for (int ni = 0; ni < 2; ni++)
        acc[mi][ni] = __builtin_amdgcn_mfma_f32_16x16x32_bf16(a[mi], b[ni], acc[mi][ni], 0, 0, 0);
    __syncthreads();
  }
  int fg = lane >> 4;
#pragma unroll
  for (int mi = 0; mi < 4; mi++)
#pragma unroll
    for (int r = 0; r < 4; r++) {
      int p = row0 + wr * 64 + mi * 16 + fg * 4 + r;
      if (p >= rend) continue;
      int t = pair_token[p];
      float wtp = pair_wt[p];
#pragma unroll
      for (int ni = 0; ni < 2; ni++) {
        int c = col0 + wc * 32 + ni * 16 + fr;
        float val = (acc[mi][ni][r] + bd[e * 1024 + c]) * wtp;
        atomicAdd(&out[(size_t)t * 1024 + c], val);
      }
    }
}

extern "C" void kernel_launch(void* const* d_in, const int* in_sizes, int n_in, void* d_out,
                              int out_size, void* d_ws, size_t ws_size, hipStream_t stream) {
  const float* hs   = (const float*)d_in[0];
  const int*   pos  = (const int*)d_in[1];
  const float* ln1  = (const float*)d_in[2];
  const float* ln2  = (const float*)d_in[3];
  const float* wq   = (const float*)d_in[4];
  const float* wk   = (const float*)d_in[5];
  const float* wv   = (const float*)d_in[6];
  const float* wo   = (const float*)d_in[7];
  const float* sinks = (const float*)d_in[8];
  const float* rw   = (const float*)d_in[9];
  const float* rb   = (const float*)d_in[10];
  const float* wg   = (const float*)d_in[11];
  const float* bg   = (const float*)d_in[12];
  const float* wu   = (const float*)d_in[13];
  const float* bu   = (const float*)d_in[14];
  const float* wd   = (const float*)d_in[15];
  const float* bd   = (const float*)d_in[16];
  float* out = (float*)d_out;

  float* ws = (float*)d_ws;
  size_t o = 0;
  auto alloc = [&](size_t nfloats) { float* p = ws + o; o += (nfloats + 3) & ~(size_t)3; return p; };
  float* cosb  = alloc(SQ * 32);
  float* sinb  = alloc(SQ * 32);
  float* x1    = alloc((size_t)SQ * 1024);
  float* qb    = alloc((size_t)SQ * 1024);
  float* kbuf  = alloc((size_t)SQ * 256);
  float* vbuf  = alloc((size_t)SQ * 256);
  float* attnb = alloc((size_t)SQ * 1024);
  float* x2    = alloc((size_t)SQ * 1024);
  unsigned short* x2bf   = (unsigned short*)alloc((size_t)SQ * 1024 / 2);
  unsigned short* hmidbf = (unsigned short*)alloc((size_t)MAXP * 1024 / 2);
  float* pair_wt = alloc(MAXP);
  float* top4w = alloc(SQ * 4);
  int* ib = (int*)alloc(MAXP + SQ * 4 + 32 + 32 + 33 + 1 + 3 * MAXTILES + 8);
  int* pair_token = ib; ib += MAXP;
  int* top4i  = ib; ib += SQ * 4;
  int* counts = ib; ib += 32;
  int* cursor = ib; ib += 32;
  int* offs   = ib; ib += 33;
  int* ntiles = ib; ib += 1;
  int* tile_e = ib; ib += MAXTILES;
  int* tile_row = ib; ib += MAXTILES;
  int* tile_end = ib; ib += MAXTILES;

  hipMemsetAsync(counts, 0, 64 * sizeof(int), stream);

  k_rope_table<<<SQ, 32, 0, stream>>>(pos, cosb, sinb);
  k_rmsnorm<<<SQ, 256, 0, stream>>>(hs, ln1, x1);
  k_gemm<<<dim3(16, 32), 256, 0, stream>>>(x1, wq, nullptr, qb, 1024);
  k_gemm<<<dim3(4, 32), 256, 0, stream>>>(x1, wk, nullptr, kbuf, 256);
  k_gemm<<<dim3(4, 32), 256, 0, stream>>>(x1, wv, nullptr, vbuf, 256);
  k_rope_apply<<<SQ, 256, 0, stream>>>(qb, kbuf, cosb, sinb);
  k_attn<<<dim3(SQ / 4, NHEAD), 256, 0, stream>>>(qb, kbuf, vbuf, sinks, attnb);
  k_gemm<<<dim3(16, 32), 256, 0, stream>>>(attnb, wo, hs, out, 1024);  // out = hs + attn@wo
  k_rmsnorm<<<SQ, 256, 0, stream>>>(out, ln2, x2);
  k_cvt_bf16<<<(SQ * 1024) / (256 * 4), 256, 0, stream>>>(x2, x2bf);
  k_router<<<SQ, 64, 0, stream>>>(x2, rw, rb, top4i, top4w, counts);
  k_offsets<<<1, 1, 0, stream>>>(counts, offs, ntiles, tile_e, tile_row, tile_end);
  k_scatter<<<(SQ + 255) / 256, 256, 0, stream>>>(top4i, top4w, offs, cursor, pair_token, pair_wt);
  k_moe_gate_up_mfma<<<dim3(16, MAXTILES), 256, 0, stream>>>(
      x2bf, wg, bg, wu, bu, pair_token, tile_e, tile_row, tile_end, ntiles, hmidbf);
  k_moe_down_mfma<<<dim3(16, MAXTILES), 256, 0, stream>>>(
      hmidbf, wd, bd, pair_token, pair_wt, tile_e, tile_row, tile_end, ntiles, out);
}